// Round 1
// baseline (265.134 us; speedup 1.0000x reference)
//
#include <hip/hip_runtime.h>

// GCN autoencoder: N=50000, E=800000, 128 -> 16 -> 128.
// Round 9: attack the latency-bound aggregation kernels (k3/k4 were ~150 us
// combined at VALUBusy 6%, HBM 6%, occupancy 40% -> uncovered HBM gather
// latency; FETCH ~= 8x zs = per-XCD L2 replication of the random-src gather).
//  - Channel-sliced aggregation: features stored as 8 planes of float2
//    ([slice][node], 400 KB/plane). Block (bucket,slice) with slice = bid&7
//    pins each slice to one XCD (round-robin block->XCD mapping), so each
//    XCD's gather working set is 400 KB -> L2-resident -> ~200cy hits
//    instead of ~900cy HBM misses.
//  - 4096 blocks x 256 threads (8 blocks/CU, 32 waves) instead of 512x1024
//    (2 blocks/CU, occupancy 40%).
//  - Decoder W2 GEMM can no longer fuse (block only holds 2 channels) ->
//    separate streaming k5 (25.6 MB write, memory-bound, ~6 us).
//  - k1 (bucket scatter + h1 GEMM) unchanged this round; k2 additionally
//    emits the dinv-scaled h1 in sliced-float2 layout.

#define N_NODES 50000
#define N_EDGES 800000
#define D_IN    128
#define D_H     16
#define K_BUCK  512
#define NPB2    98       // nodes per bucket: bucket = dst / 98 (max 49999/98 = 510)
#define BSHIFT  11
#define BCAP    (1 << BSHIFT)   // 2048 slots; mean 1562, sd 40 -> 12 sigma margin
#define PA_BLKS 256
#define PA_CHUNK 3125    // 800000/256
#define GC_PAD  16       // gcur stride in ints (64 B line padding)
#define NSLICE  8        // 8 slices x 2 channels; slice = blockIdx & 7 -> XCD

// ---- K1: fused [phase A bucket scatter (blocks 0..255)] + [h1 GEMM] ----
__global__ __launch_bounds__(256) void k1_fused(
        const int* __restrict__ src, const int* __restrict__ dst,
        const float* __restrict__ x, const float* __restrict__ W1,
        int* __restrict__ gcur, float* __restrict__ h1, int* __restrict__ arr) {
    __shared__ float w1s[D_IN * D_H];   // GEMM segment (8 KB)
    __shared__ int hist[K_BUCK];        // phase A segment (2+2 KB)
    __shared__ int cur[K_BUCK];
    int bid = blockIdx.x;
    int tid = threadIdx.x;

    if (bid < PA_BLKS) {
        // ---- phase A: bucket scatter of packed (src<<7 | local_dst) ----
        int e0 = bid * PA_CHUNK;
        for (int b = tid; b < K_BUCK; b += 256) hist[b] = 0;
        __syncthreads();
        for (int i = tid; i < PA_CHUNK; i += 256) {
            int d = dst[e0 + i];
            atomicAdd(&hist[d / NPB2], 1);
        }
        __syncthreads();
        for (int b = tid; b < K_BUCK; b += 256)
            cur[b] = (b << BSHIFT) + atomicAdd(&gcur[b * GC_PAD], hist[b]);
        __syncthreads();
        for (int i = tid; i < PA_CHUNK; i += 256) {
            int d = dst[e0 + i];
            int s = src[e0 + i];
            int b = d / NPB2;
            int pos = atomicAdd(&cur[b], 1);
            if (pos < ((b + 1) << BSHIFT))       // overflow guard (12 sigma)
                arr[pos] = (s << 7) | (d - b * NPB2);
        }
    } else {
        // ---- h1 = x @ W1 ----
        for (int i = tid; i < D_IN * D_H; i += 256) w1s[i] = W1[i];
        __syncthreads();
        int idx = (bid - PA_BLKS) * 256 + tid;   // < 800000 exactly
        int row = idx >> 4;
        int col = idx & 15;
        const float4* xr = (const float4*)(x + row * D_IN);
        float acc = 0.0f;
        #pragma unroll
        for (int k4 = 0; k4 < D_IN / 4; ++k4) {
            float4 v = xr[k4];
            acc += v.x * w1s[(k4 * 4 + 0) * D_H + col];
            acc += v.y * w1s[(k4 * 4 + 1) * D_H + col];
            acc += v.z * w1s[(k4 * 4 + 2) * D_H + col];
            acc += v.w * w1s[(k4 * 4 + 3) * D_H + col];
        }
        h1[idx] = acc;
    }
}

// ---- K2: per-bucket degree -> dinv; emit h1s = h1*dinv in sliced-float2
//      layout h1s2[slice*N + node] = {h1s[node][2s], h1s[node][2s+1]} ----
__global__ __launch_bounds__(256) void k2_deg_scale(
        const int* __restrict__ arr, const int* __restrict__ gcur,
        const float* __restrict__ h1, float* __restrict__ dinv,
        float2* __restrict__ h1s2) {
    __shared__ int cnt[NPB2];
    __shared__ float sdi[NPB2];
    int k = blockIdx.x, tid = threadIdx.x;
    for (int i = tid; i < NPB2; i += 256) cnt[i] = 0;
    __syncthreads();
    int count = min(gcur[k * GC_PAD], BCAP);
    int base = k << BSHIFT;
    for (int i = tid; i < count; i += 256) atomicAdd(&cnt[arr[base + i] & 127], 1);
    __syncthreads();
    int n0 = k * NPB2;
    int ncnt = min(NPB2, N_NODES - n0);
    for (int i = tid; i < ncnt; i += 256) {
        float di = rsqrtf((float)cnt[i] + 1.0f);   // +1 = self loop
        sdi[i] = di;
        dinv[n0 + i] = di;
    }
    __syncthreads();
    for (int g = tid; g < ncnt * NSLICE; g += 256) {
        int i = g >> 3;
        int s = g & 7;
        float di = sdi[i];
        float2 v = *(const float2*)(h1 + (n0 + i) * D_H + 2 * s);
        v.x *= di; v.y *= di;
        h1s2[s * N_NODES + n0 + i] = v;
    }
}

// ---- K3: encoder aggregation, one (bucket, channel-slice) per block.
//      zs2[s][i] = di*( di*(h1s_self + S h1s[src]) + b1[2s..2s+1] ) ----
__global__ __launch_bounds__(256, 8) void k3_agg_enc(
        const float2* __restrict__ h1s2, const int* __restrict__ arr,
        const int* __restrict__ gcur, const float* __restrict__ dinv,
        const float* __restrict__ b1, float2* __restrict__ zs2) {
    __shared__ float acc0[112];   // NPB2 rounded up (bank stagger)
    __shared__ float acc1[112];
    int s = blockIdx.x & 7;       // slice -> XCD (round-robin bid%8)
    int k = blockIdx.x >> 3;      // bucket
    int tid = threadIdx.x;
    for (int i = tid; i < NPB2; i += 256) { acc0[i] = 0.0f; acc1[i] = 0.0f; }
    __syncthreads();
    int count = min(gcur[k * GC_PAD], BCAP);
    int base = k << BSHIFT;
    const float2* __restrict__ fs = h1s2 + s * N_NODES;   // 400 KB plane
    int i = tid;
    for (; i + 768 < count; i += 1024) {
        int p0 = arr[base + i];
        int p1 = arr[base + i + 256];
        int p2 = arr[base + i + 512];
        int p3 = arr[base + i + 768];
        float2 v0 = fs[p0 >> 7];
        float2 v1 = fs[p1 >> 7];
        float2 v2 = fs[p2 >> 7];
        float2 v3 = fs[p3 >> 7];
        atomicAdd(&acc0[p0 & 127], v0.x); atomicAdd(&acc1[p0 & 127], v0.y);
        atomicAdd(&acc0[p1 & 127], v1.x); atomicAdd(&acc1[p1 & 127], v1.y);
        atomicAdd(&acc0[p2 & 127], v2.x); atomicAdd(&acc1[p2 & 127], v2.y);
        atomicAdd(&acc0[p3 & 127], v3.x); atomicAdd(&acc1[p3 & 127], v3.y);
    }
    for (; i < count; i += 256) {
        int p = arr[base + i];
        float2 v = fs[p >> 7];
        atomicAdd(&acc0[p & 127], v.x); atomicAdd(&acc1[p & 127], v.y);
    }
    __syncthreads();
    int n0 = k * NPB2;
    int ncnt = min(NPB2, N_NODES - n0);
    float b1x = b1[2 * s], b1y = b1[2 * s + 1];
    for (int j = tid; j < ncnt; j += 256) {
        int n = n0 + j;
        float di = dinv[n];
        float2 h = fs[n];                     // self term (already *dinv)
        float2 z;
        z.x = di * (di * (acc0[j] + h.x) + b1x);
        z.y = di * (di * (acc1[j] + h.y) + b1y);
        zs2[s * N_NODES + n] = z;             // zs = z*dinv, pre-scaled
    }
}

// ---- K4: decoder aggregation (sliced); ag2[s][i] = di*(S zs[src] + zs_self) ----
__global__ __launch_bounds__(256, 8) void k4_agg_dec(
        const float2* __restrict__ zs2, const int* __restrict__ arr,
        const int* __restrict__ gcur, const float* __restrict__ dinv,
        float2* __restrict__ ag2) {
    __shared__ float acc0[112];
    __shared__ float acc1[112];
    int s = blockIdx.x & 7;
    int k = blockIdx.x >> 3;
    int tid = threadIdx.x;
    for (int i = tid; i < NPB2; i += 256) { acc0[i] = 0.0f; acc1[i] = 0.0f; }
    __syncthreads();
    int count = min(gcur[k * GC_PAD], BCAP);
    int base = k << BSHIFT;
    const float2* __restrict__ fs = zs2 + s * N_NODES;
    int i = tid;
    for (; i + 768 < count; i += 1024) {
        int p0 = arr[base + i];
        int p1 = arr[base + i + 256];
        int p2 = arr[base + i + 512];
        int p3 = arr[base + i + 768];
        float2 v0 = fs[p0 >> 7];
        float2 v1 = fs[p1 >> 7];
        float2 v2 = fs[p2 >> 7];
        float2 v3 = fs[p3 >> 7];
        atomicAdd(&acc0[p0 & 127], v0.x); atomicAdd(&acc1[p0 & 127], v0.y);
        atomicAdd(&acc0[p1 & 127], v1.x); atomicAdd(&acc1[p1 & 127], v1.y);
        atomicAdd(&acc0[p2 & 127], v2.x); atomicAdd(&acc1[p2 & 127], v2.y);
        atomicAdd(&acc0[p3 & 127], v3.x); atomicAdd(&acc1[p3 & 127], v3.y);
    }
    for (; i < count; i += 256) {
        int p = arr[base + i];
        float2 v = fs[p >> 7];
        atomicAdd(&acc0[p & 127], v.x); atomicAdd(&acc1[p & 127], v.y);
    }
    __syncthreads();
    int n0 = k * NPB2;
    int ncnt = min(NPB2, N_NODES - n0);
    for (int j = tid; j < ncnt; j += 256) {
        int n = n0 + j;
        float di = dinv[n];
        float2 zf = fs[n];                    // self term (zs pre-scaled)
        float2 a;
        a.x = di * (acc0[j] + zf.x);
        a.y = di * (acc1[j] + zf.y);
        ag2[s * N_NODES + n] = a;
    }
}

// ---- K5: out[n][:] = b2 + ag2[n][:16] @ W2   (streaming, float4 stores) ----
__global__ __launch_bounds__(256) void k5_out(
        const float2* __restrict__ ag2, const float* __restrict__ W2,
        const float* __restrict__ b2, float* __restrict__ out) {
    __shared__ __align__(16) float w2s[D_H * D_IN];   // 8 KB
    int tid = threadIdx.x;
    for (int i = tid; i < D_H * D_IN; i += 256) w2s[i] = W2[i];
    __syncthreads();
    int idx = blockIdx.x * 256 + tid;   // over N*32 = 1.6M exactly
    int n = idx >> 5;
    int j4 = idx & 31;
    float a[D_H];
    #pragma unroll
    for (int sp = 0; sp < NSLICE; ++sp) {
        float2 v = ag2[sp * N_NODES + n];   // broadcast within 32-lane group
        a[2 * sp] = v.x; a[2 * sp + 1] = v.y;
    }
    const float4* w2s4 = (const float4*)w2s;
    float4 v = ((const float4*)b2)[j4];
    #pragma unroll
    for (int c = 0; c < D_H; ++c) {
        float ac = a[c];
        float4 w = w2s4[c * (D_IN / 4) + j4];
        v.x += ac * w.x; v.y += ac * w.y; v.z += ac * w.z; v.w += ac * w.w;
    }
    ((float4*)out)[idx] = v;
}

extern "C" void kernel_launch(void* const* d_in, const int* in_sizes, int n_in,
                              void* d_out, int out_size, void* d_ws, size_t ws_size,
                              hipStream_t stream) {
    const float* x  = (const float*)d_in[0];
    const int*   ei = (const int*)d_in[1];   // [2, E]: src then dst
    const float* W1 = (const float*)d_in[2];
    const float* b1 = (const float*)d_in[3];
    const float* W2 = (const float*)d_in[4];
    const float* b2 = (const float*)d_in[5];
    float* out = (float*)d_out;

    const int* src = ei;
    const int* dst = ei + N_EDGES;

    // ws carve: gcur[512*16] | dinv[N] | h1[N*16] | h1s2[8N f2] | zs2[8N f2]
    //           | ag2[8N f2] | arr[512*2048]   (~17.2 MB)
    char* base = (char*)d_ws;
    int*    gcur = (int*)base;                 base += K_BUCK * GC_PAD * 4;
    float*  dinv = (float*)base;               base += N_NODES * 4;
    float*  h1   = (float*)base;               base += N_NODES * D_H * 4;
    float2* h1s2 = (float2*)base;              base += NSLICE * N_NODES * 8;
    float2* zs2  = (float2*)base;              base += NSLICE * N_NODES * 8;
    float2* ag2  = (float2*)base;              base += NSLICE * N_NODES * 8;
    int*    arr  = (int*)base;                 base += K_BUCK * BCAP * 4;

    hipMemsetAsync(gcur, 0, K_BUCK * GC_PAD * sizeof(int), stream);

    k1_fused<<<PA_BLKS + (N_NODES * D_H / 256), 256, 0, stream>>>(src, dst, x, W1, gcur, h1, arr);
    k2_deg_scale<<<K_BUCK, 256, 0, stream>>>(arr, gcur, h1, dinv, h1s2);
    k3_agg_enc<<<K_BUCK * NSLICE, 256, 0, stream>>>(h1s2, arr, gcur, dinv, b1, zs2);
    k4_agg_dec<<<K_BUCK * NSLICE, 256, 0, stream>>>(zs2, arr, gcur, dinv, ag2);
    k5_out<<<N_NODES * 32 / 256, 256, 0, stream>>>(ag2, W2, b2, out);
}

// Round 2
// 167.059 us; speedup vs baseline: 1.5871x; 1.5871x over previous
//
#include <hip/hip_runtime.h>

// GCN autoencoder: N=50000, E=800000, 128 -> 16 -> 128.
// Round 10: CSR restructure. R9 post-mortem showed the agg kernels are bound
// by lane-level memory-op ISSUE rate (~32 lane-ops/edge from 8-16x edge
// replication + LDS atomics), not latency (occupancy 40->65% changed nothing).
//  - k2 now counting-sorts each bucket's edges by dst -> csr[] (src indices
//    grouped per node) + meta[n] = (row_start, count). +3 ops/edge, once.
//  - k3/k4: 4 lanes per node, float4 register accumulators. Per edge:
//    1 coalesced idx load + 1 shfl broadcast + 4 float4 gather lanes
//    (one full 64B line per edge) and ZERO atomics. ~6 lane-ops/edge.
//  - k4 re-fuses the W2 GEMM + b2 + out write (block owns all 16 channels).
//  - feature layout back to plain row-major [n][16] (float4 view); slicing
//    removed.

#define N_NODES 50000
#define N_EDGES 800000
#define D_IN    128
#define D_H     16
#define K_BUCK  512
#define NPB2    98       // nodes per bucket: bucket = dst / 98 (max 49999/98 = 510)
#define BSHIFT  11
#define BCAP    (1 << BSHIFT)   // 2048 slots; mean 1562, sd 40 -> 12 sigma margin
#define PA_BLKS 500
#define PA_CHUNK 1600    // 500*1600 = 800000
#define GC_PAD  16       // gcur stride in ints (64 B line padding)

// ---- K1: fused [phase A bucket scatter (blocks 0..499)] + [h1 GEMM] ----
__global__ __launch_bounds__(256) void k1_fused(
        const int* __restrict__ src, const int* __restrict__ dst,
        const float* __restrict__ x, const float* __restrict__ W1,
        int* __restrict__ gcur, float* __restrict__ h1, int* __restrict__ arr) {
    __shared__ float w1s[D_IN * D_H];   // GEMM segment (8 KB)
    __shared__ int hist[K_BUCK];        // phase A segment (2+2 KB)
    __shared__ int cur[K_BUCK];
    int bid = blockIdx.x;
    int tid = threadIdx.x;

    if (bid < PA_BLKS) {
        // ---- phase A: bucket scatter of packed (src<<7 | local_dst) ----
        int e0 = bid * PA_CHUNK;
        for (int b = tid; b < K_BUCK; b += 256) hist[b] = 0;
        __syncthreads();
        for (int i = tid; i < PA_CHUNK; i += 256) {
            int d = dst[e0 + i];
            atomicAdd(&hist[d / NPB2], 1);
        }
        __syncthreads();
        for (int b = tid; b < K_BUCK; b += 256)
            cur[b] = (b << BSHIFT) + atomicAdd(&gcur[b * GC_PAD], hist[b]);
        __syncthreads();
        for (int i = tid; i < PA_CHUNK; i += 256) {
            int d = dst[e0 + i];
            int s = src[e0 + i];
            int b = d / NPB2;
            int pos = atomicAdd(&cur[b], 1);
            if (pos < ((b + 1) << BSHIFT))       // overflow guard (12 sigma)
                arr[pos] = (s << 7) | (d - b * NPB2);
        }
    } else {
        // ---- h1 = x @ W1 ----
        for (int i = tid; i < D_IN * D_H; i += 256) w1s[i] = W1[i];
        __syncthreads();
        int idx = (bid - PA_BLKS) * 256 + tid;   // < 800000 exactly
        int row = idx >> 4;
        int col = idx & 15;
        const float4* xr = (const float4*)(x + row * D_IN);
        float acc = 0.0f;
        #pragma unroll
        for (int k4 = 0; k4 < D_IN / 4; ++k4) {
            float4 v = xr[k4];
            acc += v.x * w1s[(k4 * 4 + 0) * D_H + col];
            acc += v.y * w1s[(k4 * 4 + 1) * D_H + col];
            acc += v.z * w1s[(k4 * 4 + 2) * D_H + col];
            acc += v.w * w1s[(k4 * 4 + 3) * D_H + col];
        }
        h1[idx] = acc;
    }
}

// ---- K2: per-bucket counting sort -> CSR; dinv; scale h1 *= dinv in place ----
__global__ __launch_bounds__(256) void k2_build_csr(
        const int* __restrict__ arr, const int* __restrict__ gcur,
        float* __restrict__ h1, float* __restrict__ dinv,
        int* __restrict__ csr, int2* __restrict__ meta) {
    __shared__ int cnt[NPB2];
    __shared__ int pref[NPB2];
    __shared__ int cur[NPB2];
    __shared__ float sdi[NPB2];
    int k = blockIdx.x, tid = threadIdx.x;
    for (int i = tid; i < NPB2; i += 256) cnt[i] = 0;
    __syncthreads();
    int count = min(gcur[k * GC_PAD], BCAP);
    int base = k << BSHIFT;
    for (int i = tid; i < count; i += 256) atomicAdd(&cnt[arr[base + i] & 127], 1);
    __syncthreads();
    if (tid == 0) {
        int run = 0;
        for (int l = 0; l < NPB2; ++l) { pref[l] = run; run += cnt[l]; }
    }
    __syncthreads();
    int n0 = k * NPB2;
    int ncnt = min(NPB2, N_NODES - n0);
    for (int l = tid; l < ncnt; l += 256) {
        cur[l] = pref[l];
        meta[n0 + l] = make_int2(base + pref[l], cnt[l]);
        float di = rsqrtf((float)cnt[l] + 1.0f);   // +1 = self loop
        sdi[l] = di;
        dinv[n0 + l] = di;
    }
    __syncthreads();
    // scale h1 in place: h1s[n][:] = h1[n][:] * dinv[n]
    for (int g = tid; g < ncnt * 4; g += 256) {
        int l = g >> 2;
        float di = sdi[l];
        float4* p = (float4*)(h1 + (n0 + l) * D_H);
        float4 v = p[g & 3];
        v.x *= di; v.y *= di; v.z *= di; v.w *= di;
        p[g & 3] = v;
    }
    // scatter to csr (grouped by local dst)
    for (int i = tid; i < count; i += 256) {
        int p = arr[base + i];
        int l = p & 127;
        int pos = atomicAdd(&cur[l], 1);
        csr[base + pos] = p >> 7;
    }
}

// ---- K3: encoder agg, 4 lanes/node, register accumulate.
//      zs[n][:] = di*( di*(h1s_self + S h1s[src]) + b1 )   (pre-scaled z) ----
__global__ __launch_bounds__(256) void k3_agg_enc(
        const float4* __restrict__ h1s4, const int* __restrict__ csr,
        const int2* __restrict__ meta, const float* __restrict__ dinv,
        const float* __restrict__ b1, float4* __restrict__ zs4) {
    int tid = threadIdx.x;
    int q = tid & 3;
    int n = blockIdx.x * 64 + (tid >> 2);
    if (n >= N_NODES) return;
    int qb = tid & 60;                 // quad base lane within wave
    int2 m = meta[n];                  // same addr across quad -> broadcast
    int e = m.x, end = m.x + m.y;
    float4 acc = {0.0f, 0.0f, 0.0f, 0.0f};
    for (; e < end; e += 4) {
        int myidx = 0;
        if (e + q < end) myidx = csr[e + q];   // coalesced 16B per quad
        #pragma unroll
        for (int j = 0; j < 4; ++j) {
            int idx = __shfl(myidx, qb + j, 64);
            if (e + j < end) {
                float4 v = h1s4[idx * 4 + q];  // quad covers one 64B line
                acc.x += v.x; acc.y += v.y; acc.z += v.z; acc.w += v.w;
            }
        }
    }
    float di = dinv[n];
    float4 hv = h1s4[n * 4 + q];       // self (already *dinv)
    float4 bv = ((const float4*)b1)[q];
    float4 z;
    z.x = di * (di * (acc.x + hv.x) + bv.x);
    z.y = di * (di * (acc.y + hv.y) + bv.y);
    z.z = di * (di * (acc.z + hv.z) + bv.z);
    z.w = di * (di * (acc.w + hv.w) + bv.w);
    zs4[n * 4 + q] = z;
}

// ---- K4: decoder agg (same structure) fused with W2 GEMM + b2 + out ----
__global__ __launch_bounds__(256) void k4_agg_dec_out(
        const float4* __restrict__ zs4, const int* __restrict__ csr,
        const int2* __restrict__ meta, const float* __restrict__ dinv,
        const float* __restrict__ W2, const float* __restrict__ b2,
        float* __restrict__ out) {
    __shared__ __align__(16) float agL[64 * D_H];     // 4 KB
    __shared__ __align__(16) float w2s[D_H * D_IN];   // 8 KB
    int tid = threadIdx.x;
    for (int i = tid; i < D_H * D_IN; i += 256) w2s[i] = W2[i];
    int q = tid & 3;
    int nloc = tid >> 2;
    int n = blockIdx.x * 64 + nloc;
    int qb = tid & 60;
    if (n < N_NODES) {
        int2 m = meta[n];
        int e = m.x, end = m.x + m.y;
        float4 acc = {0.0f, 0.0f, 0.0f, 0.0f};
        for (; e < end; e += 4) {
            int myidx = 0;
            if (e + q < end) myidx = csr[e + q];
            #pragma unroll
            for (int j = 0; j < 4; ++j) {
                int idx = __shfl(myidx, qb + j, 64);
                if (e + j < end) {
                    float4 v = zs4[idx * 4 + q];
                    acc.x += v.x; acc.y += v.y; acc.z += v.z; acc.w += v.w;
                }
            }
        }
        float di = dinv[n];
        float4 zv = zs4[n * 4 + q];    // self (zs pre-scaled)
        float4 a;
        a.x = di * (acc.x + zv.x);
        a.y = di * (acc.y + zv.y);
        a.z = di * (acc.z + zv.z);
        a.w = di * (acc.w + zv.w);
        ((float4*)agL)[nloc * 4 + q] = a;
    }
    __syncthreads();
    // out[n][:] = b2 + agL[nloc][:16] @ W2 ; thread = (nloc, col-quad q*8..)
    int total = min(64, N_NODES - (int)blockIdx.x * 64);
    if (nloc < total) {
        const float* arow = &agL[nloc * D_H];
        const float4* w2s4 = (const float4*)w2s;
        float4 o[8];
        #pragma unroll
        for (int u = 0; u < 8; ++u) o[u] = ((const float4*)b2)[q * 8 + u];
        #pragma unroll
        for (int c = 0; c < D_H; ++c) {
            float ac = arow[c];
            #pragma unroll
            for (int u = 0; u < 8; ++u) {
                float4 w = w2s4[c * (D_IN / 4) + q * 8 + u];
                o[u].x += ac * w.x; o[u].y += ac * w.y;
                o[u].z += ac * w.z; o[u].w += ac * w.w;
            }
        }
        float4* orow = (float4*)(out + n * D_IN);
        #pragma unroll
        for (int u = 0; u < 8; ++u) orow[q * 8 + u] = o[u];
    }
}

extern "C" void kernel_launch(void* const* d_in, const int* in_sizes, int n_in,
                              void* d_out, int out_size, void* d_ws, size_t ws_size,
                              hipStream_t stream) {
    const float* x  = (const float*)d_in[0];
    const int*   ei = (const int*)d_in[1];   // [2, E]: src then dst
    const float* W1 = (const float*)d_in[2];
    const float* b1 = (const float*)d_in[3];
    const float* W2 = (const float*)d_in[4];
    const float* b2 = (const float*)d_in[5];
    float* out = (float*)d_out;

    const int* src = ei;
    const int* dst = ei + N_EDGES;

    // ws carve: gcur | dinv[N] | h1[N*16] | zs[N*16] | meta[N int2]
    //           | arr[512*2048] | csr[512*2048]   (~15.2 MB)
    char* base = (char*)d_ws;
    int*    gcur = (int*)base;                 base += K_BUCK * GC_PAD * 4;
    float*  dinv = (float*)base;               base += N_NODES * 4;
    float*  h1   = (float*)base;               base += N_NODES * D_H * 4;
    float*  zs   = (float*)base;               base += N_NODES * D_H * 4;
    int2*   meta = (int2*)base;                base += N_NODES * 8;
    int*    arr  = (int*)base;                 base += K_BUCK * BCAP * 4;
    int*    csr  = (int*)base;                 base += K_BUCK * BCAP * 4;

    hipMemsetAsync(gcur, 0, K_BUCK * GC_PAD * sizeof(int), stream);

    k1_fused<<<PA_BLKS + (N_NODES * D_H / 256), 256, 0, stream>>>(src, dst, x, W1, gcur, h1, arr);
    k2_build_csr<<<K_BUCK, 256, 0, stream>>>(arr, gcur, h1, dinv, csr, meta);
    k3_agg_enc<<<(N_NODES + 63) / 64, 256, 0, stream>>>((const float4*)h1, csr, meta, dinv, b1, (float4*)zs);
    k4_agg_dec_out<<<(N_NODES + 63) / 64, 256, 0, stream>>>((const float4*)zs, csr, meta, dinv, W2, b2, out);
}

// Round 3
// 161.966 us; speedup vs baseline: 1.6370x; 1.0314x over previous
//
#include <hip/hip_runtime.h>

// GCN autoencoder: N=50000, E=800000, 128 -> 16 -> 128.
// Round 11: kill the scalar-LDS-read GEMMs.
//  - R10 counters: k1 44 us at 11% HBM / 7% VALU -> issue-bound on 128
//    ds_read_b32 per thread (16-bank pattern) in the h1 GEMM half.
//  - k1 GEMM: thread-per-row, 16 reg accumulators; W1 read from LDS at a
//    WAVE-UNIFORM address per step (same-addr broadcast, conflict-free),
//    4:1 FMA:LDS inst ratio, 50K threads instead of 800K.
//  - k4: 512-thr blocks / 128 nodes. Agg (4 lanes/node, CSR, shfl quad) ->
//    agL LDS (stride 17, bank-clean), epilogue thread=(quarter=tid>>7, n):
//    quarter is wave-aligned so w2s reads are same-addr broadcasts; 32
//    outputs in registers (was 128 ds_read_b128/thread).
//  - phase A: int4 edge loads (4x fewer VMEM insts).
//  - k2, k3 unchanged from R10 (CSR build + encoder agg).

#define N_NODES 50000
#define N_EDGES 800000
#define D_IN    128
#define D_H     16
#define K_BUCK  512
#define NPB2    98       // nodes per bucket: bucket = dst / 98 (max 49999/98 = 510)
#define BSHIFT  11
#define BCAP    (1 << BSHIFT)   // 2048 slots; mean 1562, sd 40 -> 12 sigma margin
#define PA_BLKS 500
#define PA_CHUNK 1600    // 500*1600 = 800000
#define GC_PAD  16       // gcur stride in ints (64 B line padding)
#define G_BLKS  196      // ceil(50000/256) GEMM blocks (thread-per-row)
#define K4_NPB  128      // nodes per k4 block (512 threads)

// ---- K1: fused [phase A bucket scatter (blocks 0..499)] + [h1 GEMM] ----
__global__ __launch_bounds__(256) void k1_fused(
        const int* __restrict__ src, const int* __restrict__ dst,
        const float* __restrict__ x, const float* __restrict__ W1,
        int* __restrict__ gcur, float* __restrict__ h1, int* __restrict__ arr) {
    __shared__ __align__(16) float w1s[D_IN * D_H];   // GEMM segment (8 KB)
    __shared__ int hist[K_BUCK];        // phase A segment (2+2 KB)
    __shared__ int cur[K_BUCK];
    int bid = blockIdx.x;
    int tid = threadIdx.x;

    if (bid < PA_BLKS) {
        // ---- phase A: bucket scatter of packed (src<<7 | local_dst) ----
        int e0 = bid * PA_CHUNK;
        for (int b = tid; b < K_BUCK; b += 256) hist[b] = 0;
        __syncthreads();
        const int4* d4p = (const int4*)(dst + e0);
        const int4* s4p = (const int4*)(src + e0);
        for (int i = tid; i < PA_CHUNK / 4; i += 256) {
            int4 d = d4p[i];
            atomicAdd(&hist[d.x / NPB2], 1);
            atomicAdd(&hist[d.y / NPB2], 1);
            atomicAdd(&hist[d.z / NPB2], 1);
            atomicAdd(&hist[d.w / NPB2], 1);
        }
        __syncthreads();
        for (int b = tid; b < K_BUCK; b += 256)
            cur[b] = (b << BSHIFT) + atomicAdd(&gcur[b * GC_PAD], hist[b]);
        __syncthreads();
        for (int i = tid; i < PA_CHUNK / 4; i += 256) {
            int4 d = d4p[i];
            int4 s = s4p[i];
            int b0 = d.x / NPB2, b1 = d.y / NPB2, b2 = d.z / NPB2, b3 = d.w / NPB2;
            int p0 = atomicAdd(&cur[b0], 1);
            int p1 = atomicAdd(&cur[b1], 1);
            int p2 = atomicAdd(&cur[b2], 1);
            int p3 = atomicAdd(&cur[b3], 1);
            if (p0 < ((b0 + 1) << BSHIFT)) arr[p0] = (s.x << 7) | (d.x - b0 * NPB2);
            if (p1 < ((b1 + 1) << BSHIFT)) arr[p1] = (s.y << 7) | (d.y - b1 * NPB2);
            if (p2 < ((b2 + 1) << BSHIFT)) arr[p2] = (s.z << 7) | (d.z - b2 * NPB2);
            if (p3 < ((b3 + 1) << BSHIFT)) arr[p3] = (s.w << 7) | (d.w - b3 * NPB2);
        }
    } else {
        // ---- h1 = x @ W1: thread-per-row, wave-uniform W1 broadcasts ----
        for (int i = tid; i < D_IN * D_H; i += 256) w1s[i] = W1[i];
        __syncthreads();
        int row = (bid - PA_BLKS) * 256 + tid;
        if (row >= N_NODES) return;
        const float4* xr = (const float4*)(x + row * D_IN);
        const float4* w4 = (const float4*)w1s;
        float4 a0 = {0, 0, 0, 0}, a1 = a0, a2 = a0, a3 = a0;
        for (int k4 = 0; k4 < D_IN / 4; ++k4) {
            float4 xv = xr[k4];
            #pragma unroll
            for (int j = 0; j < 4; ++j) {
                float xk = (j == 0) ? xv.x : (j == 1) ? xv.y : (j == 2) ? xv.z : xv.w;
                const float4* wr = w4 + (k4 * 4 + j) * 4;   // uniform across wave
                float4 w0 = wr[0], w1v = wr[1], w2v = wr[2], w3v = wr[3];
                a0.x += xk * w0.x;  a0.y += xk * w0.y;  a0.z += xk * w0.z;  a0.w += xk * w0.w;
                a1.x += xk * w1v.x; a1.y += xk * w1v.y; a1.z += xk * w1v.z; a1.w += xk * w1v.w;
                a2.x += xk * w2v.x; a2.y += xk * w2v.y; a2.z += xk * w2v.z; a2.w += xk * w2v.w;
                a3.x += xk * w3v.x; a3.y += xk * w3v.y; a3.z += xk * w3v.z; a3.w += xk * w3v.w;
            }
        }
        float4* hr = (float4*)(h1 + row * D_H);
        hr[0] = a0; hr[1] = a1; hr[2] = a2; hr[3] = a3;
    }
}

// ---- K2: per-bucket counting sort -> CSR; dinv; scale h1 *= dinv in place ----
__global__ __launch_bounds__(256) void k2_build_csr(
        const int* __restrict__ arr, const int* __restrict__ gcur,
        float* __restrict__ h1, float* __restrict__ dinv,
        int* __restrict__ csr, int2* __restrict__ meta) {
    __shared__ int cnt[NPB2];
    __shared__ int pref[NPB2];
    __shared__ int cur[NPB2];
    __shared__ float sdi[NPB2];
    int k = blockIdx.x, tid = threadIdx.x;
    for (int i = tid; i < NPB2; i += 256) cnt[i] = 0;
    __syncthreads();
    int count = min(gcur[k * GC_PAD], BCAP);
    int base = k << BSHIFT;
    for (int i = tid; i < count; i += 256) atomicAdd(&cnt[arr[base + i] & 127], 1);
    __syncthreads();
    if (tid == 0) {
        int run = 0;
        for (int l = 0; l < NPB2; ++l) { pref[l] = run; run += cnt[l]; }
    }
    __syncthreads();
    int n0 = k * NPB2;
    int ncnt = min(NPB2, N_NODES - n0);
    for (int l = tid; l < ncnt; l += 256) {
        cur[l] = pref[l];
        meta[n0 + l] = make_int2(base + pref[l], cnt[l]);
        float di = rsqrtf((float)cnt[l] + 1.0f);   // +1 = self loop
        sdi[l] = di;
        dinv[n0 + l] = di;
    }
    __syncthreads();
    // scale h1 in place: h1s[n][:] = h1[n][:] * dinv[n]
    for (int g = tid; g < ncnt * 4; g += 256) {
        int l = g >> 2;
        float di = sdi[l];
        float4* p = (float4*)(h1 + (n0 + l) * D_H);
        float4 v = p[g & 3];
        v.x *= di; v.y *= di; v.z *= di; v.w *= di;
        p[g & 3] = v;
    }
    // scatter to csr (grouped by local dst)
    for (int i = tid; i < count; i += 256) {
        int p = arr[base + i];
        int l = p & 127;
        int pos = atomicAdd(&cur[l], 1);
        csr[base + pos] = p >> 7;
    }
}

// ---- K3: encoder agg, 4 lanes/node, register accumulate.
//      zs[n][:] = di*( di*(h1s_self + S h1s[src]) + b1 )   (pre-scaled z) ----
__global__ __launch_bounds__(256) void k3_agg_enc(
        const float4* __restrict__ h1s4, const int* __restrict__ csr,
        const int2* __restrict__ meta, const float* __restrict__ dinv,
        const float* __restrict__ b1, float4* __restrict__ zs4) {
    int tid = threadIdx.x;
    int q = tid & 3;
    int n = blockIdx.x * 64 + (tid >> 2);
    if (n >= N_NODES) return;
    int qb = tid & 60;                 // quad base lane within wave
    int2 m = meta[n];                  // same addr across quad -> broadcast
    int e = m.x, end = m.x + m.y;
    float4 acc = {0.0f, 0.0f, 0.0f, 0.0f};
    for (; e < end; e += 4) {
        int myidx = 0;
        if (e + q < end) myidx = csr[e + q];   // coalesced 16B per quad
        #pragma unroll
        for (int j = 0; j < 4; ++j) {
            int idx = __shfl(myidx, qb + j, 64);
            if (e + j < end) {
                float4 v = h1s4[idx * 4 + q];  // quad covers one 64B line
                acc.x += v.x; acc.y += v.y; acc.z += v.z; acc.w += v.w;
            }
        }
    }
    float di = dinv[n];
    float4 hv = h1s4[n * 4 + q];       // self (already *dinv)
    float4 bv = ((const float4*)b1)[q];
    float4 z;
    z.x = di * (di * (acc.x + hv.x) + bv.x);
    z.y = di * (di * (acc.y + hv.y) + bv.y);
    z.z = di * (di * (acc.z + hv.z) + bv.z);
    z.w = di * (di * (acc.w + hv.w) + bv.w);
    zs4[n * 4 + q] = z;
}

// ---- K4: decoder agg (CSR quad) + W2 GEMM epilogue with uniform broadcasts ----
__global__ __launch_bounds__(512) void k4_agg_dec_out(
        const float4* __restrict__ zs4, const int* __restrict__ csr,
        const int2* __restrict__ meta, const float* __restrict__ dinv,
        const float* __restrict__ W2, const float* __restrict__ b2,
        float* __restrict__ out) {
    __shared__ float agL[K4_NPB * 17];                // 8.7 KB (pad 17: bank-clean)
    __shared__ __align__(16) float w2s[D_H * D_IN];   // 8 KB
    int tid = threadIdx.x;
    for (int i = tid; i < D_H * D_IN; i += 512) w2s[i] = W2[i];
    int q = tid & 3;
    int nloc = tid >> 2;               // 0..127
    int n0 = blockIdx.x * K4_NPB;
    int n = n0 + nloc;
    int qb = tid & 60;
    if (n < N_NODES) {
        int2 m = meta[n];
        int e = m.x, end = m.x + m.y;
        float4 acc = {0.0f, 0.0f, 0.0f, 0.0f};
        for (; e < end; e += 4) {
            int myidx = 0;
            if (e + q < end) myidx = csr[e + q];
            #pragma unroll
            for (int j = 0; j < 4; ++j) {
                int idx = __shfl(myidx, qb + j, 64);
                if (e + j < end) {
                    float4 v = zs4[idx * 4 + q];
                    acc.x += v.x; acc.y += v.y; acc.z += v.z; acc.w += v.w;
                }
            }
        }
        float di = dinv[n];
        float4 zv = zs4[n * 4 + q];    // self (zs pre-scaled)
        agL[nloc * 17 + q * 4 + 0] = di * (acc.x + zv.x);
        agL[nloc * 17 + q * 4 + 1] = di * (acc.y + zv.y);
        agL[nloc * 17 + q * 4 + 2] = di * (acc.z + zv.z);
        agL[nloc * 17 + q * 4 + 3] = di * (acc.w + zv.w);
    }
    __syncthreads();
    // epilogue: thread = (quarter = tid>>7 [wave-aligned], ne = tid&127)
    // w2s reads are same-address broadcasts across the wave (quarter uniform).
    int quarter = tid >> 7;
    int ne = tid & 127;
    if (n0 + ne < N_NODES) {
        const float* arow = &agL[ne * 17];
        float4 o[8];
        const float4* b2q = (const float4*)(b2 + quarter * 32);
        #pragma unroll
        for (int u = 0; u < 8; ++u) o[u] = b2q[u];
        #pragma unroll
        for (int c = 0; c < D_H; ++c) {
            float ac = arow[c];
            const float4* wr = (const float4*)(w2s + c * D_IN + quarter * 32);
            #pragma unroll
            for (int u = 0; u < 8; ++u) {
                float4 w = wr[u];
                o[u].x += ac * w.x; o[u].y += ac * w.y;
                o[u].z += ac * w.z; o[u].w += ac * w.w;
            }
        }
        float4* orow = (float4*)(out + (n0 + ne) * D_IN + quarter * 32);
        #pragma unroll
        for (int u = 0; u < 8; ++u) orow[u] = o[u];
    }
}

extern "C" void kernel_launch(void* const* d_in, const int* in_sizes, int n_in,
                              void* d_out, int out_size, void* d_ws, size_t ws_size,
                              hipStream_t stream) {
    const float* x  = (const float*)d_in[0];
    const int*   ei = (const int*)d_in[1];   // [2, E]: src then dst
    const float* W1 = (const float*)d_in[2];
    const float* b1 = (const float*)d_in[3];
    const float* W2 = (const float*)d_in[4];
    const float* b2 = (const float*)d_in[5];
    float* out = (float*)d_out;

    const int* src = ei;
    const int* dst = ei + N_EDGES;

    // ws carve: gcur | dinv[N] | h1[N*16] | zs[N*16] | meta[N int2]
    //           | arr[512*2048] | csr[512*2048]   (~15.2 MB)
    char* base = (char*)d_ws;
    int*    gcur = (int*)base;                 base += K_BUCK * GC_PAD * 4;
    float*  dinv = (float*)base;               base += N_NODES * 4;
    float*  h1   = (float*)base;               base += N_NODES * D_H * 4;
    float*  zs   = (float*)base;               base += N_NODES * D_H * 4;
    int2*   meta = (int2*)base;                base += N_NODES * 8;
    int*    arr  = (int*)base;                 base += K_BUCK * BCAP * 4;
    int*    csr  = (int*)base;                 base += K_BUCK * BCAP * 4;

    hipMemsetAsync(gcur, 0, K_BUCK * GC_PAD * sizeof(int), stream);

    k1_fused<<<PA_BLKS + G_BLKS, 256, 0, stream>>>(src, dst, x, W1, gcur, h1, arr);
    k2_build_csr<<<K_BUCK, 256, 0, stream>>>(arr, gcur, h1, dinv, csr, meta);
    k3_agg_enc<<<(N_NODES + 63) / 64, 256, 0, stream>>>((const float4*)h1, csr, meta, dinv, b1, (float4*)zs);
    k4_agg_dec_out<<<(N_NODES + K4_NPB - 1) / K4_NPB, 512, 0, stream>>>((const float4*)zs, csr, meta, dinv, W2, b2, out);
}